// Round 8
// baseline (275.539 us; speedup 1.0000x reference)
//
#include <hip/hip_runtime.h>
#include <hip/hip_bf16.h>
#include <math.h>

#define BB 4
#define KK 2048
#define DD 256
#define HH 8
#define HD 32
#define HALF 128
#define QUARTER 64
#define NROW 65536            // B*H*K

typedef __attribute__((ext_vector_type(8))) short bf16x8;
typedef __attribute__((ext_vector_type(4))) float f32x4;

// 1/sqrt(32) * log2(e): scores produced directly in log2 domain
#define SCALE2F (0.17677669529663687f * 1.4426950408889634f)
#define MASKNEG -3.0e38f

__device__ __forceinline__ ushort f2bf(float f) {       // RNE, for epilogues
    unsigned u = __builtin_bit_cast(unsigned, f);
    u += 0x7fffu + ((u >> 16) & 1u);
    return (ushort)(u >> 16);
}
__device__ __forceinline__ unsigned pkbf(float a, float b) {  // HW cvt path
    ushort ua = __builtin_bit_cast(ushort, __float2bfloat16(a));
    ushort ub = __builtin_bit_cast(ushort, __float2bfloat16(b));
    return (unsigned)ua | ((unsigned)ub << 16);
}

// ---------------------------------------------------------------------------
// Kernel 1: 2D RoPE fp32->bf16, plus per-(b,key) mask bias array
// ---------------------------------------------------------------------------
__global__ __launch_bounds__(256) void rope_kernel(
    const float* __restrict__ x, const int* __restrict__ coords,
    const float* __restrict__ rope_cache, const int* __restrict__ image_size_p,
    const int* __restrict__ is_ctx, int max_pos,
    ushort* __restrict__ xr16, float* __restrict__ mbias)
{
    int idx = blockIdx.x * blockDim.x + threadIdx.x;
    if (idx >= BB * KK * HALF) return;
    int p   = idx % HALF;
    int row = idx / HALF;

    float img = (float)image_size_p[0];
    float mp1 = (float)(max_pos - 1);
    int c0 = coords[row * 2 + 0];
    int c1 = coords[row * 2 + 1];
    float cy = fminf(fmaxf(((float)c0 / img) * mp1, 0.0f), mp1);
    float cx = fminf(fmaxf(((float)c1 / img) * mp1, 0.0f), mp1);
    int y_pos = (int)cy;
    int x_pos = (int)cx;

    int j, pos, base;
    if (p < QUARTER) { j = p;           pos = x_pos; base = 2 * j; }
    else             { j = p - QUARTER; pos = y_pos; base = HALF + 2 * j; }

    const float* rc = rope_cache + ((size_t)pos * QUARTER + j) * 2;
    float c = rc[0], s = rc[1];
    const float* xin = x + (size_t)row * DD + base;
    float p0 = xin[0], p1 = xin[1];
    unsigned u = (unsigned)f2bf(p0 * c - p1 * s) |
                 ((unsigned)f2bf(p0 * s + p1 * c) << 16);
    *(unsigned*)(xr16 + (size_t)row * DD + base) = u;

    if (p == 0) mbias[row] = (is_ctx[row] != 0) ? 0.0f : MASKNEG;
}

// ---------------------------------------------------------------------------
// Kernel 2: weight prep — transpose to Wt[n][k], bf16, Wq scaled by SCALE2F.
// ---------------------------------------------------------------------------
__global__ __launch_bounds__(256) void wprep_kernel(
    const float* __restrict__ Wq, const float* __restrict__ Wk,
    const float* __restrict__ Wv, const float* __restrict__ Wo,
    ushort* __restrict__ wt)
{
    int z = blockIdx.z;
    const float* W = (z == 0) ? Wq : (z == 1) ? Wk : (z == 2) ? Wv : Wo;
    float scale = (z == 0) ? SCALE2F : 1.0f;
    ushort* out = wt + (size_t)z * DD * DD;
    int r0 = blockIdx.x * 64, c0 = blockIdx.y * 64;
    int tid = threadIdx.x;
    __shared__ float t[64][65];
    #pragma unroll
    for (int i = 0; i < 4; ++i) {
        int s  = tid + i * 256;
        int row = s >> 4, c4 = (s & 15) * 4;
        float4 v = *(const float4*)(W + (size_t)(r0 + row) * DD + c0 + c4);
        t[row][c4] = v.x; t[row][c4 + 1] = v.y; t[row][c4 + 2] = v.z; t[row][c4 + 3] = v.w;
    }
    __syncthreads();
    int nl = tid >> 2, ks = (tid & 3) * 16;
    ushort buf[16];
    #pragma unroll
    for (int j = 0; j < 16; ++j) buf[j] = f2bf(t[ks + j][nl] * scale);
    *(uint4*)(out + (size_t)(c0 + nl) * DD + r0 + ks)     = *(uint4*)&buf[0];
    *(uint4*)(out + (size_t)(c0 + nl) * DD + r0 + ks + 8) = *(uint4*)&buf[8];
}

// ---------------------------------------------------------------------------
// Kernel 3/6: bf16 MFMA GEMM  C[M,256] = A[M,256] @ W + b, direct fragments.
// (unchanged from measured round-5 baseline)
// ---------------------------------------------------------------------------
__global__ __launch_bounds__(256) void mfma_gemm_kernel(
    const ushort* __restrict__ A, const ushort* __restrict__ wt,
    const float* __restrict__ b0, const float* __restrict__ b1,
    const float* __restrict__ b2,
    void* __restrict__ o0, void* __restrict__ o1, void* __restrict__ o2,
    int qkv)
{
    int zz = qkv ? blockIdx.z : 3;
    const ushort* Wt = wt + (size_t)zz * DD * DD;
    const float* bp = qkv ? ((blockIdx.z == 0) ? b0 : (blockIdx.z == 1) ? b1 : b2) : b0;
    const int mode = qkv ? ((blockIdx.z == 2) ? 1 : 0) : 2;
    const float bsc = (qkv && blockIdx.z == 0) ? SCALE2F : 1.0f;

    int m0 = blockIdx.x * 128, n0 = blockIdx.y * 64;
    int tid = threadIdx.x;
    int w = tid >> 6, l = tid & 63, lg = l >> 4, ll = l & 15;
    int mrow = m0 + w * 32;

    __shared__ ushort sm[128 * 72];   // mode0: [tok128][72]; mode1: [64][136]

    f32x4 acc[2][4];
    #pragma unroll
    for (int mt = 0; mt < 2; ++mt)
        #pragma unroll
        for (int nt = 0; nt < 4; ++nt) acc[mt][nt] = (f32x4){0.f, 0.f, 0.f, 0.f};

    const ushort* Ab = A + (size_t)mrow * DD;
    #pragma unroll
    for (int kc = 0; kc < 8; ++kc) {
        bf16x8 af0 = *(const bf16x8*)(Ab + (size_t)ll * DD + kc * 32 + lg * 8);
        bf16x8 af1 = *(const bf16x8*)(Ab + (size_t)(16 + ll) * DD + kc * 32 + lg * 8);
        bf16x8 bfr[4];
        #pragma unroll
        for (int nt = 0; nt < 4; ++nt)
            bfr[nt] = *(const bf16x8*)(Wt + (size_t)(n0 + nt * 16 + ll) * DD + kc * 32 + lg * 8);
        #pragma unroll
        for (int nt = 0; nt < 4; ++nt) {
            acc[0][nt] = __builtin_amdgcn_mfma_f32_16x16x32_bf16(af0, bfr[nt], acc[0][nt], 0, 0, 0);
            acc[1][nt] = __builtin_amdgcn_mfma_f32_16x16x32_bf16(af1, bfr[nt], acc[1][nt], 0, 0, 0);
        }
    }

    float bias[4];
    #pragma unroll
    for (int nt = 0; nt < 4; ++nt) bias[nt] = bp[n0 + nt * 16 + ll] * bsc;

    int bI = m0 >> 11, tokb = m0 & 2047;

    if (mode == 0) {            // q / k : bf16 [B,H,K,32] via LDS stage
        #pragma unroll
        for (int mt = 0; mt < 2; ++mt)
            #pragma unroll
            for (int nt = 0; nt < 4; ++nt)
                #pragma unroll
                for (int r = 0; r < 4; ++r)
                    sm[(w * 32 + mt * 16 + lg * 4 + r) * 72 + nt * 16 + ll] =
                        f2bf(acc[mt][nt][r] + bias[nt]);
        __syncthreads();
        ushort* op = (ushort*)((blockIdx.z == 0) ? o0 : o1);
        int h0 = n0 >> 5;
        #pragma unroll
        for (int i = 0; i < 4; ++i) {
            int slot  = tid + i * 256;      // 0..1023
            int hh    = slot >> 9;          // head half
            int slot2 = slot & 511;
            int tok   = slot2 >> 2, d8 = slot2 & 3;
            uint4 val = *(uint4*)&sm[tok * 72 + hh * 32 + d8 * 8];
            *(uint4*)(op + (((size_t)bI * HH + h0 + hh) * KK + tokb + tok) * HD + d8 * 8) = val;
        }
    } else if (mode == 1) {     // V^T [B,H,32,K] via LDS stage
        #pragma unroll
        for (int mt = 0; mt < 2; ++mt)
            #pragma unroll
            for (int nt = 0; nt < 4; ++nt)
                #pragma unroll
                for (int r = 0; r < 4; ++r)
                    sm[(nt * 16 + ll) * 136 + w * 32 + mt * 16 + lg * 4 + r] =
                        f2bf(acc[mt][nt][r] + bias[nt]);
        __syncthreads();
        ushort* op = (ushort*)o2;
        #pragma unroll
        for (int i = 0; i < 4; ++i) {
            int slot = tid + i * 256;       // 0..1023
            int row  = slot >> 4;           // d-local 0..63
            int t8   = slot & 15;           // token 8-group
            uint4 val = *(uint4*)&sm[row * 136 + t8 * 8];
            int n = n0 + row, hI = n >> 5, dI = n & 31;
            *(uint4*)(op + (((size_t)bI * HH + hI) * HD + dI) * KK + tokb + t8 * 8) = val;
        }
    } else {                    // fp32 out projection
        float* op = (float*)o0;
        #pragma unroll
        for (int mt = 0; mt < 2; ++mt)
            #pragma unroll
            for (int nt = 0; nt < 4; ++nt)
                #pragma unroll
                for (int r = 0; r < 4; ++r)
                    op[(size_t)(mrow + mt * 16 + lg * 4 + r) * DD + n0 + nt * 16 + ll] =
                        acc[mt][nt][r] + bias[nt];
    }
}

// ---------------------------------------------------------------------------
// Kernel 4: masked flash attention, swapped-operand MFMA, SPLIT-K (x2).
// Grid (K/64, H*2, B): blockIdx.y = h*2+split; each block does 1024 keys.
// 8 blocks/CU -> 32 waves/CU (full occupancy) for latency hiding.
// Writes unnormalized partials: pO f32 [split][row][32], pML float2 (m, l).
// Round-2 tile body (V at point of use, no setprio/prefetch) + ones-MFMA l.
// ---------------------------------------------------------------------------
__global__ __launch_bounds__(256, 8) void attn_mfma_kernel(
    const ushort* __restrict__ qb, const ushort* __restrict__ kb,
    const ushort* __restrict__ vt, const int* __restrict__ is_ctx,
    const float* __restrict__ mbias, float* __restrict__ pO,
    float* __restrict__ pML)
{
    const int b     = blockIdx.z;
    const int h     = blockIdx.y >> 1;
    const int split = blockIdx.y & 1;
    const int bh = b * HH + h;
    const int tid = threadIdx.x;
    const int w  = tid >> 6;
    const int l  = tid & 63;
    const int lg = l >> 4;
    const int ll = l & 15;
    const int q0 = blockIdx.x * 64 + w * 16;

    __shared__ ushort Pl[4][16][64];
    char* Pw = (char*)&Pl[w][0][0];
    const int sw = (ll & 7) << 4;

    bf16x8 qf = *(const bf16x8*)(qb + ((size_t)bh * KK + q0 + ll) * HD + lg * 8);
    const float qcf = (is_ctx[b * KK + q0 + ll] != 0) ? 1.0f : 0.0f;

    float m = -INFINITY;
    f32x4 acc0 = (f32x4){0.f, 0.f, 0.f, 0.f};
    f32x4 acc1 = (f32x4){0.f, 0.f, 0.f, 0.f};
    f32x4 accl = (f32x4){0.f, 0.f, 0.f, 0.f};

    const ushort* kbase = kb + (size_t)bh * KK * HD;
    const ushort* vbase = vt + (size_t)bh * HD * KK;
    const float*  mbb   = mbias + (size_t)b * KK;
    const f32x4 zero = {0.f, 0.f, 0.f, 0.f};
    const short one = (short)0x3F80;
    const bf16x8 ones = {one, one, one, one, one, one, one, one};

    const int kbeg = split << 10;           // split * 1024
    const int kend = kbeg + (KK >> 1);

    for (int kt0 = kbeg; kt0 < kend; kt0 += 64) {
        // S^T = K Q^T : row = key (quad), col = q (lane)
        f32x4 st[4];
        float4 mb[4];
        #pragma unroll
        for (int kt = 0; kt < 4; ++kt) {
            bf16x8 kf = *(const bf16x8*)(kbase + (size_t)(kt0 + kt * 16 + ll) * HD + lg * 8);
            mb[kt] = *(const float4*)(mbb + kt0 + kt * 16 + lg * 4);
            st[kt] = __builtin_amdgcn_mfma_f32_16x16x32_bf16(kf, qf, zero, 0, 0, 0);
        }
        // mask (log2 domain): s = qcf*bias_k + s
        #pragma unroll
        for (int kt = 0; kt < 4; ++kt) {
            st[kt][0] = fmaf(qcf, mb[kt].x, st[kt][0]);
            st[kt][1] = fmaf(qcf, mb[kt].y, st[kt][1]);
            st[kt][2] = fmaf(qcf, mb[kt].z, st[kt][2]);
            st[kt][3] = fmaf(qcf, mb[kt].w, st[kt][3]);
        }
        // row max: max3-fusable tree + 2 cross-group shuffles
        float g0 = fmaxf(fmaxf(st[0][0], st[0][1]), st[0][2]);
        float g1 = fmaxf(fmaxf(st[0][3], st[1][0]), st[1][1]);
        float g2 = fmaxf(fmaxf(st[1][2], st[1][3]), st[2][0]);
        float g3 = fmaxf(fmaxf(st[2][1], st[2][2]), st[2][3]);
        float g4 = fmaxf(fmaxf(st[3][0], st[3][1]), st[3][2]);
        float tmax = fmaxf(fmaxf(fmaxf(g0, g1), fmaxf(g2, g3)), fmaxf(g4, st[3][3]));
        tmax = fmaxf(tmax, __shfl_xor(tmax, 16));
        tmax = fmaxf(tmax, __shfl_xor(tmax, 32));

        if (__any(tmax > m + 8.0f)) {            // deferred rescale
            float mnew = fmaxf(fmaxf(m, tmax), -1e37f);
            float corr = __builtin_amdgcn_exp2f(m - mnew);
            m = mnew;
            #pragma unroll
            for (int r = 0; r < 4; ++r) {
                float cr = __shfl(corr, lg * 4 + r);
                acc0[r] *= cr; acc1[r] *= cr; accl[r] *= cr;
            }
        }
        float msafe = fmaxf(m, -1e37f);

        #pragma unroll
        for (int kt = 0; kt < 4; ++kt) {
            float p0 = __builtin_amdgcn_exp2f(st[kt][0] - msafe);
            float p1 = __builtin_amdgcn_exp2f(st[kt][1] - msafe);
            float p2 = __builtin_amdgcn_exp2f(st[kt][2] - msafe);
            float p3 = __builtin_amdgcn_exp2f(st[kt][3] - msafe);
            uint2 uu;
            uu.x = pkbf(p0, p1);
            uu.y = pkbf(p2, p3);
            *(uint2*)(Pw + ll * 128 + ((kt * 32 + lg * 8) ^ sw)) = uu;
        }

        // O += P V : A = P (LDS), B = V^T rows (contiguous); l via ones-MFMA
        #pragma unroll
        for (int ks = 0; ks < 2; ++ks) {
            bf16x8 pf = *(const bf16x8*)(Pw + ll * 128 + ((ks * 64 + lg * 16) ^ sw));
            #pragma unroll
            for (int dt = 0; dt < 2; ++dt) {
                bf16x8 vf = *(const bf16x8*)(vbase + (size_t)(dt * 16 + ll) * KK + kt0 + ks * 32 + lg * 8);
                if (dt == 0) acc0 = __builtin_amdgcn_mfma_f32_16x16x32_bf16(pf, vf, acc0, 0, 0, 0);
                else         acc1 = __builtin_amdgcn_mfma_f32_16x16x32_bf16(pf, vf, acc1, 0, 0, 0);
            }
            accl = __builtin_amdgcn_mfma_f32_16x16x32_bf16(pf, ones, accl, 0, 0, 0);
        }
    }

    // epilogue: write raw partials. acc row = q (lg*4+r), col = d (ll).
    #pragma unroll
    for (int r = 0; r < 4; ++r) {
        int q = q0 + lg * 4 + r;
        size_t row = (size_t)bh * KK + q;
        float* po = pO + ((size_t)split * NROW + row) * HD;
        po[ll]      = acc0[r];
        po[16 + ll] = acc1[r];
        float mq = __shfl(m, lg * 4 + r);     // m lives at lane ll==q-local
        if (ll == 0)
            *(float2*)(pML + 2 * ((size_t)split * NROW + row)) =
                make_float2(mq, accl[r]);
    }
}

// ---------------------------------------------------------------------------
// Kernel 5: combine the two split-K partials -> bf16 ao [B,K,256].
// thread = (row, 8-dim group); O = (O0*e0 + O1*e1) / (l0*e0 + l1*e1).
// ---------------------------------------------------------------------------
__global__ __launch_bounds__(256) void combine_kernel(
    const float* __restrict__ pO, const float* __restrict__ pML,
    ushort* __restrict__ ao)
{
    int idx = blockIdx.x * 256 + threadIdx.x;   // 0 .. NROW*4-1
    int g   = idx & 3;
    int row = idx >> 2;
    int bh = row >> 11, q = row & 2047;
    int b = bh >> 3, h = bh & 7;

    float2 ml0 = *(const float2*)(pML + 2 * (size_t)row);
    float2 ml1 = *(const float2*)(pML + 2 * ((size_t)NROW + row));
    float M  = fmaxf(ml0.x, ml1.x);
    float e0 = __builtin_amdgcn_exp2f(ml0.x - M);
    float e1 = __builtin_amdgcn_exp2f(ml1.x - M);
    float inv = 1.0f / fmaf(ml0.y, e0, ml1.y * e1);
    float s0 = e0 * inv, s1 = e1 * inv;

    const float* o0 = pO + (size_t)row * HD + g * 8;
    const float* o1 = o0 + (size_t)NROW * HD;
    float4 a0 = *(const float4*)o0,       a1 = *(const float4*)(o0 + 4);
    float4 c0 = *(const float4*)o1,       c1 = *(const float4*)(o1 + 4);

    ushort u[8];
    u[0] = f2bf(fmaf(a0.x, s0, c0.x * s1));
    u[1] = f2bf(fmaf(a0.y, s0, c0.y * s1));
    u[2] = f2bf(fmaf(a0.z, s0, c0.z * s1));
    u[3] = f2bf(fmaf(a0.w, s0, c0.w * s1));
    u[4] = f2bf(fmaf(a1.x, s0, c1.x * s1));
    u[5] = f2bf(fmaf(a1.y, s0, c1.y * s1));
    u[6] = f2bf(fmaf(a1.z, s0, c1.z * s1));
    u[7] = f2bf(fmaf(a1.w, s0, c1.w * s1));
    *(uint4*)(ao + ((size_t)b * KK + q) * DD + h * HD + g * 8) = *(uint4*)u;
}

// ---------------------------------------------------------------------------
extern "C" void kernel_launch(void* const* d_in, const int* in_sizes, int n_in,
                              void* d_out, int out_size, void* d_ws, size_t ws_size,
                              hipStream_t stream)
{
    const float* x        = (const float*)d_in[0];
    const int*   coords   = (const int*)  d_in[1];
    const int*   is_ctx   = (const int*)  d_in[2];
    const int*   img_sz   = (const int*)  d_in[3];
    const float* Wq       = (const float*)d_in[4];
    const float* bq       = (const float*)d_in[5];
    const float* Wk       = (const float*)d_in[6];
    const float* bk       = (const float*)d_in[7];
    const float* Wv       = (const float*)d_in[8];
    const float* bv       = (const float*)d_in[9];
    const float* Wo       = (const float*)d_in[10];
    const float* bo       = (const float*)d_in[11];
    const float* rope     = (const float*)d_in[12];

    int max_pos = in_sizes[12] / (QUARTER * 2);   // 224

    const size_t NTOK = (size_t)BB * KK;          // 8192
    const size_t NELT = NTOK * DD;                // 2,097,152 elements

    char* ws = (char*)d_ws;
    ushort* xr16  = (ushort*)(ws);                     // 4 MB
    ushort* qbf   = (ushort*)(ws + NELT * 2);          // 4 MB
    ushort* kbf   = (ushort*)(ws + NELT * 4);          // 4 MB
    ushort* vtbf  = (ushort*)(ws + NELT * 6);          // 4 MB
    ushort* ao16  = (ushort*)(ws + NELT * 8);          // 4 MB
    ushort* wt    = (ushort*)(ws + NELT * 10);         // 512 KB
    float*  mbias = (float*) (ws + NELT * 10 + 524288);          // 32 KB
    float*  pO    = (float*) (ws + NELT * 10 + 524288 + 32768);  // 16 MB
    float*  pML   = (float*) (ws + NELT * 10 + 524288 + 32768 + (size_t)2 * NROW * HD * 4); // 1 MB
    float* outp = (float*)d_out;

    // 1) RoPE -> bf16 xr + mask bias array
    {
        int total = BB * KK * HALF;
        rope_kernel<<<(total + 255) / 256, 256, 0, stream>>>(
            x, coords, rope, img_sz, is_ctx, max_pos, xr16, mbias);
    }
    // 2) weight prep: transpose + bf16 (+ SCALE2F fold into Wq)
    wprep_kernel<<<dim3(4, 4, 4), 256, 0, stream>>>(Wq, Wk, Wv, Wo, wt);
    // 3) QKV projections (bf16 MFMA)
    mfma_gemm_kernel<<<dim3(NTOK / 128, DD / 64, 3), 256, 0, stream>>>(
        xr16, wt, bq, bk, bv, qbf, kbf, vtbf, 1);
    // 4) attention, split-K x2 -> partials
    attn_mfma_kernel<<<dim3(KK / 64, HH * 2, BB), 256, 0, stream>>>(
        qbf, kbf, vtbf, is_ctx, mbias, pO, pML);
    // 5) combine partials -> bf16 ao
    combine_kernel<<<(NROW * 4) / 256, 256, 0, stream>>>(pO, pML, ao16);
    // 6) output projection (bf16 MFMA, fp32 out)
    mfma_gemm_kernel<<<dim3(NTOK / 128, DD / 64, 1), 256, 0, stream>>>(
        ao16, wt, bo, bo, bo, outp, outp, outp, 0);
}

// Round 9
// 165.062 us; speedup vs baseline: 1.6693x; 1.6693x over previous
//
#include <hip/hip_runtime.h>
#include <hip/hip_bf16.h>
#include <math.h>

#define BB 4
#define KK 2048
#define DD 256
#define HH 8
#define HD 32
#define HALF 128
#define QUARTER 64

typedef __attribute__((ext_vector_type(8))) short bf16x8;
typedef __attribute__((ext_vector_type(4))) float f32x4;

// 1/sqrt(32) * log2(e): scores produced directly in log2 domain
#define SCALE2F (0.17677669529663687f * 1.4426950408889634f)
#define MASKNEG -3.0e38f

__device__ __forceinline__ ushort f2bf(float f) {       // RNE, for epilogues
    unsigned u = __builtin_bit_cast(unsigned, f);
    u += 0x7fffu + ((u >> 16) & 1u);
    return (ushort)(u >> 16);
}
__device__ __forceinline__ unsigned pkbf(float a, float b) {  // HW cvt path
    ushort ua = __builtin_bit_cast(ushort, __float2bfloat16(a));
    ushort ub = __builtin_bit_cast(ushort, __float2bfloat16(b));
    return (unsigned)ua | ((unsigned)ub << 16);
}

// ---------------------------------------------------------------------------
// Kernel 1: 2D RoPE fp32->bf16, plus per-(b,key) mask bias array
// ---------------------------------------------------------------------------
__global__ __launch_bounds__(256) void rope_kernel(
    const float* __restrict__ x, const int* __restrict__ coords,
    const float* __restrict__ rope_cache, const int* __restrict__ image_size_p,
    const int* __restrict__ is_ctx, int max_pos,
    ushort* __restrict__ xr16, float* __restrict__ mbias)
{
    int idx = blockIdx.x * blockDim.x + threadIdx.x;
    if (idx >= BB * KK * HALF) return;
    int p   = idx % HALF;
    int row = idx / HALF;

    float img = (float)image_size_p[0];
    float mp1 = (float)(max_pos - 1);
    int c0 = coords[row * 2 + 0];
    int c1 = coords[row * 2 + 1];
    float cy = fminf(fmaxf(((float)c0 / img) * mp1, 0.0f), mp1);
    float cx = fminf(fmaxf(((float)c1 / img) * mp1, 0.0f), mp1);
    int y_pos = (int)cy;
    int x_pos = (int)cx;

    int j, pos, base;
    if (p < QUARTER) { j = p;           pos = x_pos; base = 2 * j; }
    else             { j = p - QUARTER; pos = y_pos; base = HALF + 2 * j; }

    const float* rc = rope_cache + ((size_t)pos * QUARTER + j) * 2;
    float c = rc[0], s = rc[1];
    const float* xin = x + (size_t)row * DD + base;
    float p0 = xin[0], p1 = xin[1];
    unsigned u = (unsigned)f2bf(p0 * c - p1 * s) |
                 ((unsigned)f2bf(p0 * s + p1 * c) << 16);
    *(unsigned*)(xr16 + (size_t)row * DD + base) = u;

    if (p == 0) mbias[row] = (is_ctx[row] != 0) ? 0.0f : MASKNEG;
}

// ---------------------------------------------------------------------------
// Kernel 2: weight prep — transpose to Wt[n][k], bf16, Wq scaled by SCALE2F.
// ---------------------------------------------------------------------------
__global__ __launch_bounds__(256) void wprep_kernel(
    const float* __restrict__ Wq, const float* __restrict__ Wk,
    const float* __restrict__ Wv, const float* __restrict__ Wo,
    ushort* __restrict__ wt)
{
    int z = blockIdx.z;
    const float* W = (z == 0) ? Wq : (z == 1) ? Wk : (z == 2) ? Wv : Wo;
    float scale = (z == 0) ? SCALE2F : 1.0f;
    ushort* out = wt + (size_t)z * DD * DD;
    int r0 = blockIdx.x * 64, c0 = blockIdx.y * 64;
    int tid = threadIdx.x;
    __shared__ float t[64][65];
    #pragma unroll
    for (int i = 0; i < 4; ++i) {
        int s  = tid + i * 256;
        int row = s >> 4, c4 = (s & 15) * 4;
        float4 v = *(const float4*)(W + (size_t)(r0 + row) * DD + c0 + c4);
        t[row][c4] = v.x; t[row][c4 + 1] = v.y; t[row][c4 + 2] = v.z; t[row][c4 + 3] = v.w;
    }
    __syncthreads();
    int nl = tid >> 2, ks = (tid & 3) * 16;
    ushort buf[16];
    #pragma unroll
    for (int j = 0; j < 16; ++j) buf[j] = f2bf(t[ks + j][nl] * scale);
    *(uint4*)(out + (size_t)(c0 + nl) * DD + r0 + ks)     = *(uint4*)&buf[0];
    *(uint4*)(out + (size_t)(c0 + nl) * DD + r0 + ks + 8) = *(uint4*)&buf[8];
}

// ---------------------------------------------------------------------------
// Kernel 3/5: bf16 MFMA GEMM  C[M,256] = A[M,256] @ W + b, direct fragments.
// qkv=1: z=0,1 -> bf16 [B,H,K,32] (q,k); z=2 -> bf16 V^T [B,H,32,K].
// qkv=0: fp32 row-major (out projection, wt slot 3).
// ---------------------------------------------------------------------------
__global__ __launch_bounds__(256) void mfma_gemm_kernel(
    const ushort* __restrict__ A, const ushort* __restrict__ wt,
    const float* __restrict__ b0, const float* __restrict__ b1,
    const float* __restrict__ b2,
    void* __restrict__ o0, void* __restrict__ o1, void* __restrict__ o2,
    int qkv)
{
    int zz = qkv ? blockIdx.z : 3;
    const ushort* Wt = wt + (size_t)zz * DD * DD;
    const float* bp = qkv ? ((blockIdx.z == 0) ? b0 : (blockIdx.z == 1) ? b1 : b2) : b0;
    const int mode = qkv ? ((blockIdx.z == 2) ? 1 : 0) : 2;
    const float bsc = (qkv && blockIdx.z == 0) ? SCALE2F : 1.0f;

    int m0 = blockIdx.x * 128, n0 = blockIdx.y * 64;
    int tid = threadIdx.x;
    int w = tid >> 6, l = tid & 63, lg = l >> 4, ll = l & 15;
    int mrow = m0 + w * 32;

    __shared__ ushort sm[128 * 72];   // mode0: [tok128][72]; mode1: [64][136]

    f32x4 acc[2][4];
    #pragma unroll
    for (int mt = 0; mt < 2; ++mt)
        #pragma unroll
        for (int nt = 0; nt < 4; ++nt) acc[mt][nt] = (f32x4){0.f, 0.f, 0.f, 0.f};

    const ushort* Ab = A + (size_t)mrow * DD;
    #pragma unroll
    for (int kc = 0; kc < 8; ++kc) {
        bf16x8 af0 = *(const bf16x8*)(Ab + (size_t)ll * DD + kc * 32 + lg * 8);
        bf16x8 af1 = *(const bf16x8*)(Ab + (size_t)(16 + ll) * DD + kc * 32 + lg * 8);
        bf16x8 bfr[4];
        #pragma unroll
        for (int nt = 0; nt < 4; ++nt)
            bfr[nt] = *(const bf16x8*)(Wt + (size_t)(n0 + nt * 16 + ll) * DD + kc * 32 + lg * 8);
        #pragma unroll
        for (int nt = 0; nt < 4; ++nt) {
            acc[0][nt] = __builtin_amdgcn_mfma_f32_16x16x32_bf16(af0, bfr[nt], acc[0][nt], 0, 0, 0);
            acc[1][nt] = __builtin_amdgcn_mfma_f32_16x16x32_bf16(af1, bfr[nt], acc[1][nt], 0, 0, 0);
        }
    }

    float bias[4];
    #pragma unroll
    for (int nt = 0; nt < 4; ++nt) bias[nt] = bp[n0 + nt * 16 + ll] * bsc;

    int bI = m0 >> 11, tokb = m0 & 2047;

    if (mode == 0) {            // q / k : bf16 [B,H,K,32] via LDS stage
        #pragma unroll
        for (int mt = 0; mt < 2; ++mt)
            #pragma unroll
            for (int nt = 0; nt < 4; ++nt)
                #pragma unroll
                for (int r = 0; r < 4; ++r)
                    sm[(w * 32 + mt * 16 + lg * 4 + r) * 72 + nt * 16 + ll] =
                        f2bf(acc[mt][nt][r] + bias[nt]);
        __syncthreads();
        ushort* op = (ushort*)((blockIdx.z == 0) ? o0 : o1);
        int h0 = n0 >> 5;
        #pragma unroll
        for (int i = 0; i < 4; ++i) {
            int slot  = tid + i * 256;      // 0..1023
            int hh    = slot >> 9;          // head half
            int slot2 = slot & 511;
            int tok   = slot2 >> 2, d8 = slot2 & 3;
            uint4 val = *(uint4*)&sm[tok * 72 + hh * 32 + d8 * 8];
            *(uint4*)(op + (((size_t)bI * HH + h0 + hh) * KK + tokb + tok) * HD + d8 * 8) = val;
        }
    } else if (mode == 1) {     // V^T [B,H,32,K] via LDS stage
        #pragma unroll
        for (int mt = 0; mt < 2; ++mt)
            #pragma unroll
            for (int nt = 0; nt < 4; ++nt)
                #pragma unroll
                for (int r = 0; r < 4; ++r)
                    sm[(nt * 16 + ll) * 136 + w * 32 + mt * 16 + lg * 4 + r] =
                        f2bf(acc[mt][nt][r] + bias[nt]);
        __syncthreads();
        ushort* op = (ushort*)o2;
        #pragma unroll
        for (int i = 0; i < 4; ++i) {
            int slot = tid + i * 256;       // 0..1023
            int row  = slot >> 4;           // d-local 0..63
            int t8   = slot & 15;           // token 8-group
            uint4 val = *(uint4*)&sm[row * 136 + t8 * 8];
            int n = n0 + row, hI = n >> 5, dI = n & 31;
            *(uint4*)(op + (((size_t)bI * HH + hI) * HD + dI) * KK + tokb + t8 * 8) = val;
        }
    } else {                    // fp32 out projection
        float* op = (float*)o0;
        #pragma unroll
        for (int mt = 0; mt < 2; ++mt)
            #pragma unroll
            for (int nt = 0; nt < 4; ++nt)
                #pragma unroll
                for (int r = 0; r < 4; ++r)
                    op[(size_t)(mrow + mt * 16 + lg * 4 + r) * DD + n0 + nt * 16 + ll] =
                        acc[mt][nt][r] + bias[nt];
    }
}

// ---------------------------------------------------------------------------
// Kernel 4: masked flash attention, swapped-operand MFMA, with block-level
// double-buffered LDS staging of K and V tiles (T3-minimum + T14).
// Grid (K/64, H, B), 256 thr = 4 waves; wave owns 16 q rows.
// Per tile: commit regs->LDS(buf p) -> barrier -> issue next-tile global
// loads to regs (latency hides under compute) -> compute from LDS(buf p).
// One barrier/tile (buf X reads in iter t; next X writes in iter t+2,
// separated by iter t+1's barrier). Padded LDS rows: K 80B, V 136B ->
// <=2-way bank conflicts on ds_read_b128.
// ---------------------------------------------------------------------------
__global__ __launch_bounds__(256, 4) void attn_mfma_kernel(
    const ushort* __restrict__ qb, const ushort* __restrict__ kb,
    const ushort* __restrict__ vt, const int* __restrict__ is_ctx,
    const float* __restrict__ mbias, ushort* __restrict__ ao)
{
    const int b  = blockIdx.z;
    const int h  = blockIdx.y;
    const int bh = b * HH + h;
    const int tid = threadIdx.x;
    const int w  = tid >> 6;
    const int l  = tid & 63;
    const int lg = l >> 4;
    const int ll = l & 15;
    const int q0 = blockIdx.x * 64 + w * 16;

    __shared__ ushort Ks[2][64][40];   // 64 keys x 32 dims, 80B rows (pad 16B)
    __shared__ ushort Vs[2][32][68];   // 32 dims x 64 keys, 136B rows (pad 8B)
    __shared__ ushort Pl[4][16][64];
    char* Pw = (char*)&Pl[w][0][0];
    const int sw = (ll & 7) << 4;

    bf16x8 qf = *(const bf16x8*)(qb + ((size_t)bh * KK + q0 + ll) * HD + lg * 8);
    const float qcf = (is_ctx[b * KK + q0 + ll] != 0) ? 1.0f : 0.0f;

    float m = -INFINITY;
    f32x4 acc0 = (f32x4){0.f, 0.f, 0.f, 0.f};
    f32x4 acc1 = (f32x4){0.f, 0.f, 0.f, 0.f};
    f32x4 accl = (f32x4){0.f, 0.f, 0.f, 0.f};

    const ushort* kbase = kb + (size_t)bh * KK * HD;
    const ushort* vbase = vt + (size_t)bh * HD * KK;
    const float*  mbb   = mbias + (size_t)b * KK;
    const f32x4 zero = {0.f, 0.f, 0.f, 0.f};
    const short one = (short)0x3F80;
    const bf16x8 ones = {one, one, one, one, one, one, one, one};

    // staging decomposition: 256 threads x 16B cover each tile
    const int krow = tid >> 2, kblk = tid & 3;   // K: key row, 16B block
    const int vrow = tid >> 3, vkc  = tid & 7;   // V: dim row, 16B key-chunk

    uint4 kreg = *(const uint4*)(kbase + (size_t)krow * HD + kblk * 8);
    uint4 vreg = *(const uint4*)(vbase + (size_t)vrow * KK + vkc * 8);

    int p = 0;
    for (int kt0 = 0; kt0 < KK; kt0 += 64) {
        // commit tile kt0 to LDS buffer p (implicit vmcnt wait on kreg/vreg)
        *(uint4*)&Ks[p][krow][kblk * 8] = kreg;
        *(uint4*)&Vs[p][vrow][vkc * 8]  = vreg;
        __syncthreads();
        // issue next tile's global loads; land during this tile's compute
        if (kt0 + 64 < KK) {
            kreg = *(const uint4*)(kbase + (size_t)(kt0 + 64 + krow) * HD + kblk * 8);
            vreg = *(const uint4*)(vbase + (size_t)vrow * KK + kt0 + 64 + vkc * 8);
        }

        // S^T = K Q^T : row = key (quad), col = q (lane)
        f32x4 st[4];
        float4 mb[4];
        #pragma unroll
        for (int kt = 0; kt < 4; ++kt) {
            bf16x8 kf = *(const bf16x8*)&Ks[p][kt * 16 + ll][lg * 8];
            mb[kt] = *(const float4*)(mbb + kt0 + kt * 16 + lg * 4);
            st[kt] = __builtin_amdgcn_mfma_f32_16x16x32_bf16(kf, qf, zero, 0, 0, 0);
        }
        // mask (log2 domain): s = qcf*bias_k + s
        #pragma unroll
        for (int kt = 0; kt < 4; ++kt) {
            st[kt][0] = fmaf(qcf, mb[kt].x, st[kt][0]);
            st[kt][1] = fmaf(qcf, mb[kt].y, st[kt][1]);
            st[kt][2] = fmaf(qcf, mb[kt].z, st[kt][2]);
            st[kt][3] = fmaf(qcf, mb[kt].w, st[kt][3]);
        }
        // row max: max3-fusable tree + 2 cross-group shuffles
        float g0 = fmaxf(fmaxf(st[0][0], st[0][1]), st[0][2]);
        float g1 = fmaxf(fmaxf(st[0][3], st[1][0]), st[1][1]);
        float g2 = fmaxf(fmaxf(st[1][2], st[1][3]), st[2][0]);
        float g3 = fmaxf(fmaxf(st[2][1], st[2][2]), st[2][3]);
        float g4 = fmaxf(fmaxf(st[3][0], st[3][1]), st[3][2]);
        float tmax = fmaxf(fmaxf(fmaxf(g0, g1), fmaxf(g2, g3)), fmaxf(g4, st[3][3]));
        tmax = fmaxf(tmax, __shfl_xor(tmax, 16));
        tmax = fmaxf(tmax, __shfl_xor(tmax, 32));

        if (__any(tmax > m + 8.0f)) {            // deferred rescale
            float mnew = fmaxf(fmaxf(m, tmax), -1e37f);
            float corr = __builtin_amdgcn_exp2f(m - mnew);
            m = mnew;
            #pragma unroll
            for (int r = 0; r < 4; ++r) {
                float cr = __shfl(corr, lg * 4 + r);
                acc0[r] *= cr; acc1[r] *= cr; accl[r] *= cr;
            }
        }
        float msafe = fmaxf(m, -1e37f);

        #pragma unroll
        for (int kt = 0; kt < 4; ++kt) {
            float p0 = __builtin_amdgcn_exp2f(st[kt][0] - msafe);
            float p1 = __builtin_amdgcn_exp2f(st[kt][1] - msafe);
            float p2 = __builtin_amdgcn_exp2f(st[kt][2] - msafe);
            float p3 = __builtin_amdgcn_exp2f(st[kt][3] - msafe);
            uint2 uu;
            uu.x = pkbf(p0, p1);
            uu.y = pkbf(p2, p3);
            *(uint2*)(Pw + ll * 128 + ((kt * 32 + lg * 8) ^ sw)) = uu;
        }

        // O += P V : A = P (LDS), B = V rows from LDS; l via ones-MFMA
        #pragma unroll
        for (int ks = 0; ks < 2; ++ks) {
            bf16x8 pf = *(const bf16x8*)(Pw + ll * 128 + ((ks * 64 + lg * 16) ^ sw));
            #pragma unroll
            for (int dt = 0; dt < 2; ++dt) {
                bf16x8 vf = *(const bf16x8*)&Vs[p][dt * 16 + ll][ks * 32 + lg * 8];
                if (dt == 0) acc0 = __builtin_amdgcn_mfma_f32_16x16x32_bf16(pf, vf, acc0, 0, 0, 0);
                else         acc1 = __builtin_amdgcn_mfma_f32_16x16x32_bf16(pf, vf, acc1, 0, 0, 0);
            }
            accl = __builtin_amdgcn_mfma_f32_16x16x32_bf16(pf, ones, accl, 0, 0, 0);
        }
        p ^= 1;
    }

    // epilogue: l lives in accl (all cols equal) -> no shuffles
    #pragma unroll
    for (int r = 0; r < 4; ++r) {
        float inv = 1.0f / accl[r];
        int q = q0 + lg * 4 + r;
        ushort* orow = ao + ((size_t)b * KK + q) * DD + h * HD;
        orow[ll]      = f2bf(acc0[r] * inv);
        orow[16 + ll] = f2bf(acc1[r] * inv);
    }
}

// ---------------------------------------------------------------------------
extern "C" void kernel_launch(void* const* d_in, const int* in_sizes, int n_in,
                              void* d_out, int out_size, void* d_ws, size_t ws_size,
                              hipStream_t stream)
{
    const float* x        = (const float*)d_in[0];
    const int*   coords   = (const int*)  d_in[1];
    const int*   is_ctx   = (const int*)  d_in[2];
    const int*   img_sz   = (const int*)  d_in[3];
    const float* Wq       = (const float*)d_in[4];
    const float* bq       = (const float*)d_in[5];
    const float* Wk       = (const float*)d_in[6];
    const float* bk       = (const float*)d_in[7];
    const float* Wv       = (const float*)d_in[8];
    const float* bv       = (const float*)d_in[9];
    const float* Wo       = (const float*)d_in[10];
    const float* bo       = (const float*)d_in[11];
    const float* rope     = (const float*)d_in[12];

    int max_pos = in_sizes[12] / (QUARTER * 2);   // 224

    const size_t NTOK = (size_t)BB * KK;          // 8192
    const size_t NELT = NTOK * DD;                // 2,097,152 elements

    char* ws = (char*)d_ws;
    ushort* xr16  = (ushort*)(ws);                     // 4 MB
    ushort* qbf   = (ushort*)(ws + NELT * 2);          // 4 MB
    ushort* kbf   = (ushort*)(ws + NELT * 4);          // 4 MB
    ushort* vtbf  = (ushort*)(ws + NELT * 6);          // 4 MB
    ushort* ao16  = (ushort*)(ws + NELT * 8);          // 4 MB
    ushort* wt    = (ushort*)(ws + NELT * 10);         // 512 KB
    float*  mbias = (float*) (ws + NELT * 10 + 524288);          // 32 KB
    float* outp = (float*)d_out;

    // 1) RoPE -> bf16 xr + mask bias array
    {
        int total = BB * KK * HALF;
        rope_kernel<<<(total + 255) / 256, 256, 0, stream>>>(
            x, coords, rope, img_sz, is_ctx, max_pos, xr16, mbias);
    }
    // 2) weight prep: transpose + bf16 (+ SCALE2F fold into Wq)
    wprep_kernel<<<dim3(4, 4, 4), 256, 0, stream>>>(Wq, Wk, Wv, Wo, wt);
    // 3) QKV projections (bf16 MFMA)
    mfma_gemm_kernel<<<dim3(NTOK / 128, DD / 64, 3), 256, 0, stream>>>(
        xr16, wt, bq, bk, bv, qbf, kbf, vtbf, 1);
    // 4) attention (LDS-staged double-buffered K/V) -> bf16 ao
    attn_mfma_kernel<<<dim3(KK / 64, HH, BB), 256, 0, stream>>>(
        qbf, kbf, vtbf, is_ctx, mbias, ao16);
    // 5) output projection (bf16 MFMA, fp32 out)
    mfma_gemm_kernel<<<dim3(NTOK / 128, DD / 64, 1), 256, 0, stream>>>(
        ao16, wt, bo, bo, bo, outp, outp, outp, 0);
}

// Round 10
// 155.575 us; speedup vs baseline: 1.7711x; 1.0610x over previous
//
#include <hip/hip_runtime.h>
#include <hip/hip_bf16.h>
#include <math.h>

#define BB 4
#define KK 2048
#define DD 256
#define HH 8
#define HD 32
#define HALF 128
#define QUARTER 64

typedef __attribute__((ext_vector_type(8))) short bf16x8;
typedef __attribute__((ext_vector_type(4))) float f32x4;

// 1/sqrt(32) * log2(e): scores produced directly in log2 domain
#define SCALE2F (0.17677669529663687f * 1.4426950408889634f)
#define MASKNEG -3.0e38f

__device__ __forceinline__ ushort f2bf(float f) {       // RNE, for epilogues
    unsigned u = __builtin_bit_cast(unsigned, f);
    u += 0x7fffu + ((u >> 16) & 1u);
    return (ushort)(u >> 16);
}
__device__ __forceinline__ unsigned pkbf(float a, float b) {  // HW cvt path
    ushort ua = __builtin_bit_cast(ushort, __float2bfloat16(a));
    ushort ub = __builtin_bit_cast(ushort, __float2bfloat16(b));
    return (unsigned)ua | ((unsigned)ub << 16);
}

// ---------------------------------------------------------------------------
// Kernel 1: 2D RoPE fp32->bf16, plus per-(b,key) mask bias array
// ---------------------------------------------------------------------------
__global__ __launch_bounds__(256) void rope_kernel(
    const float* __restrict__ x, const int* __restrict__ coords,
    const float* __restrict__ rope_cache, const int* __restrict__ image_size_p,
    const int* __restrict__ is_ctx, int max_pos,
    ushort* __restrict__ xr16, float* __restrict__ mbias)
{
    int idx = blockIdx.x * blockDim.x + threadIdx.x;
    if (idx >= BB * KK * HALF) return;
    int p   = idx % HALF;
    int row = idx / HALF;

    float img = (float)image_size_p[0];
    float mp1 = (float)(max_pos - 1);
    int c0 = coords[row * 2 + 0];
    int c1 = coords[row * 2 + 1];
    float cy = fminf(fmaxf(((float)c0 / img) * mp1, 0.0f), mp1);
    float cx = fminf(fmaxf(((float)c1 / img) * mp1, 0.0f), mp1);
    int y_pos = (int)cy;
    int x_pos = (int)cx;

    int j, pos, base;
    if (p < QUARTER) { j = p;           pos = x_pos; base = 2 * j; }
    else             { j = p - QUARTER; pos = y_pos; base = HALF + 2 * j; }

    const float* rc = rope_cache + ((size_t)pos * QUARTER + j) * 2;
    float c = rc[0], s = rc[1];
    const float* xin = x + (size_t)row * DD + base;
    float p0 = xin[0], p1 = xin[1];
    unsigned u = (unsigned)f2bf(p0 * c - p1 * s) |
                 ((unsigned)f2bf(p0 * s + p1 * c) << 16);
    *(unsigned*)(xr16 + (size_t)row * DD + base) = u;

    if (p == 0) mbias[row] = (is_ctx[row] != 0) ? 0.0f : MASKNEG;
}

// ---------------------------------------------------------------------------
// Kernel 2: weight prep — transpose to Wt[n][k], bf16, Wq scaled by SCALE2F.
// ---------------------------------------------------------------------------
__global__ __launch_bounds__(256) void wprep_kernel(
    const float* __restrict__ Wq, const float* __restrict__ Wk,
    const float* __restrict__ Wv, const float* __restrict__ Wo,
    ushort* __restrict__ wt)
{
    int z = blockIdx.z;
    const float* W = (z == 0) ? Wq : (z == 1) ? Wk : (z == 2) ? Wv : Wo;
    float scale = (z == 0) ? SCALE2F : 1.0f;
    ushort* out = wt + (size_t)z * DD * DD;
    int r0 = blockIdx.x * 64, c0 = blockIdx.y * 64;
    int tid = threadIdx.x;
    __shared__ float t[64][65];
    #pragma unroll
    for (int i = 0; i < 4; ++i) {
        int s  = tid + i * 256;
        int row = s >> 4, c4 = (s & 15) * 4;
        float4 v = *(const float4*)(W + (size_t)(r0 + row) * DD + c0 + c4);
        t[row][c4] = v.x; t[row][c4 + 1] = v.y; t[row][c4 + 2] = v.z; t[row][c4 + 3] = v.w;
    }
    __syncthreads();
    int nl = tid >> 2, ks = (tid & 3) * 16;
    ushort buf[16];
    #pragma unroll
    for (int j = 0; j < 16; ++j) buf[j] = f2bf(t[ks + j][nl] * scale);
    *(uint4*)(out + (size_t)(c0 + nl) * DD + r0 + ks)     = *(uint4*)&buf[0];
    *(uint4*)(out + (size_t)(c0 + nl) * DD + r0 + ks + 8) = *(uint4*)&buf[8];
}

// ---------------------------------------------------------------------------
// Kernel 3/5: bf16 MFMA GEMM, 64x64 tile, LDS double-buffered pipeline
// (round-9 attn staging pattern). 4 waves x 16 M-rows; K-step 32, 8 steps.
// Per step: commit regs->LDS(p), barrier, issue next-step global loads,
// compute 4 MFMAs/wave from padded LDS (80B rows).
// qkv=1: z=0,1 -> bf16 [B,H,K,32] (q,k); z=2 -> bf16 V^T [B,H,32,K].
// qkv=0: fp32 row-major (out projection, wt slot 3).
// ---------------------------------------------------------------------------
__global__ __launch_bounds__(256, 6) void mfma_gemm_kernel(
    const ushort* __restrict__ A, const ushort* __restrict__ wt,
    const float* __restrict__ b0, const float* __restrict__ b1,
    const float* __restrict__ b2,
    void* __restrict__ o0, void* __restrict__ o1, void* __restrict__ o2,
    int qkv)
{
    int zz = qkv ? blockIdx.z : 3;
    const ushort* Wt = wt + (size_t)zz * DD * DD;
    const float* bp = qkv ? ((blockIdx.z == 0) ? b0 : (blockIdx.z == 1) ? b1 : b2) : b0;
    const int mode = qkv ? ((blockIdx.z == 2) ? 1 : 0) : 2;
    const float bsc = (qkv && blockIdx.z == 0) ? SCALE2F : 1.0f;

    int m0 = blockIdx.x * 64, n0 = blockIdx.y * 64;
    int tid = threadIdx.x;
    int w = tid >> 6, l = tid & 63, lg = l >> 4, ll = l & 15;

    // LDS: As[2][64][40] at [0,5120), Ws[2][64][40] at [5120,10240) (ushorts)
    // 80B rows -> 16B-aligned b128 ops. Epilogue aliases lds[0..4608).
    __shared__ ushort lds[10240];
    #define AS_(p, r, k) lds[(p) * 2560 + (r) * 40 + (k)]
    #define WS_(p, r, k) lds[5120 + (p) * 2560 + (r) * 40 + (k)]

    f32x4 acc[4];
    #pragma unroll
    for (int nt = 0; nt < 4; ++nt) acc[nt] = (f32x4){0.f, 0.f, 0.f, 0.f};

    // staging decomposition: 256 thr x 16B cover each 64x32 tile
    const int srow = tid >> 2, sseg = tid & 3;

    const ushort* Ab = A  + (size_t)(m0 + srow) * DD + sseg * 8;
    const ushort* Wb = Wt + (size_t)(n0 + srow) * DD + sseg * 8;

    uint4 areg = *(const uint4*)Ab;
    uint4 wreg = *(const uint4*)Wb;

    int p = 0;
    #pragma unroll
    for (int kc = 0; kc < 8; ++kc) {
        *(uint4*)&AS_(p, srow, sseg * 8) = areg;
        *(uint4*)&WS_(p, srow, sseg * 8) = wreg;
        __syncthreads();
        if (kc < 7) {
            areg = *(const uint4*)(Ab + (kc + 1) * 32);
            wreg = *(const uint4*)(Wb + (kc + 1) * 32);
        }
        bf16x8 af = *(const bf16x8*)&AS_(p, w * 16 + ll, lg * 8);
        #pragma unroll
        for (int nt = 0; nt < 4; ++nt) {
            bf16x8 bfr = *(const bf16x8*)&WS_(p, nt * 16 + ll, lg * 8);
            acc[nt] = __builtin_amdgcn_mfma_f32_16x16x32_bf16(af, bfr, acc[nt], 0, 0, 0);
        }
        p ^= 1;
    }

    float bias[4];
    #pragma unroll
    for (int nt = 0; nt < 4; ++nt) bias[nt] = bp[n0 + nt * 16 + ll] * bsc;

    int bI = m0 >> 11, tokb = m0 & 2047;

    if (mode == 0) {            // q / k : bf16 [B,H,K,32] via LDS stage
        __syncthreads();        // done with staging buffers
        #pragma unroll
        for (int nt = 0; nt < 4; ++nt)
            #pragma unroll
            for (int r = 0; r < 4; ++r)
                lds[(w * 16 + lg * 4 + r) * 72 + nt * 16 + ll] =
                    f2bf(acc[nt][r] + bias[nt]);
        __syncthreads();
        ushort* op = (ushort*)((blockIdx.z == 0) ? o0 : o1);
        int h0 = n0 >> 5;
        #pragma unroll
        for (int i = 0; i < 2; ++i) {
            int slot = tid + i * 256;       // 0..511
            int tok  = slot >> 3, seg = slot & 7;
            int hh   = seg >> 2, d8 = seg & 3;
            uint4 val = *(uint4*)&lds[tok * 72 + seg * 8];
            *(uint4*)(op + (((size_t)bI * HH + h0 + hh) * KK + tokb + tok) * HD + d8 * 8) = val;
        }
    } else if (mode == 1) {     // V^T [B,H,32,K] via LDS stage
        __syncthreads();
        #pragma unroll
        for (int nt = 0; nt < 4; ++nt)
            #pragma unroll
            for (int r = 0; r < 4; ++r)
                lds[(nt * 16 + ll) * 72 + w * 16 + lg * 4 + r] =
                    f2bf(acc[nt][r] + bias[nt]);
        __syncthreads();
        ushort* op = (ushort*)o2;
        #pragma unroll
        for (int i = 0; i < 2; ++i) {
            int slot = tid + i * 256;       // 0..511
            int row  = slot >> 3;           // n-local 0..63
            int t8   = slot & 7;            // token 8-group
            uint4 val = *(uint4*)&lds[row * 72 + t8 * 8];
            int n = n0 + row, hI = n >> 5, dI = n & 31;
            *(uint4*)(op + (((size_t)bI * HH + hI) * HD + dI) * KK + tokb + t8 * 8) = val;
        }
    } else {                    // fp32 out projection
        float* op = (float*)o0;
        #pragma unroll
        for (int nt = 0; nt < 4; ++nt)
            #pragma unroll
            for (int r = 0; r < 4; ++r)
                op[(size_t)(m0 + w * 16 + lg * 4 + r) * DD + n0 + nt * 16 + ll] =
                    acc[nt][r] + bias[nt];
    }
    #undef AS_
    #undef WS_
}

// ---------------------------------------------------------------------------
// Kernel 4: masked flash attention, swapped-operand MFMA, with block-level
// double-buffered LDS staging of K and V tiles (unchanged from round 9).
// ---------------------------------------------------------------------------
__global__ __launch_bounds__(256, 4) void attn_mfma_kernel(
    const ushort* __restrict__ qb, const ushort* __restrict__ kb,
    const ushort* __restrict__ vt, const int* __restrict__ is_ctx,
    const float* __restrict__ mbias, ushort* __restrict__ ao)
{
    const int b  = blockIdx.z;
    const int h  = blockIdx.y;
    const int bh = b * HH + h;
    const int tid = threadIdx.x;
    const int w  = tid >> 6;
    const int l  = tid & 63;
    const int lg = l >> 4;
    const int ll = l & 15;
    const int q0 = blockIdx.x * 64 + w * 16;

    __shared__ ushort Ks[2][64][40];   // 64 keys x 32 dims, 80B rows
    __shared__ ushort Vs[2][32][68];   // 32 dims x 64 keys, 136B rows
    __shared__ ushort Pl[4][16][64];
    char* Pw = (char*)&Pl[w][0][0];
    const int sw = (ll & 7) << 4;

    bf16x8 qf = *(const bf16x8*)(qb + ((size_t)bh * KK + q0 + ll) * HD + lg * 8);
    const float qcf = (is_ctx[b * KK + q0 + ll] != 0) ? 1.0f : 0.0f;

    float m = -INFINITY;
    f32x4 acc0 = (f32x4){0.f, 0.f, 0.f, 0.f};
    f32x4 acc1 = (f32x4){0.f, 0.f, 0.f, 0.f};
    f32x4 accl = (f32x4){0.f, 0.f, 0.f, 0.f};

    const ushort* kbase = kb + (size_t)bh * KK * HD;
    const ushort* vbase = vt + (size_t)bh * HD * KK;
    const float*  mbb   = mbias + (size_t)b * KK;
    const f32x4 zero = {0.f, 0.f, 0.f, 0.f};
    const short one = (short)0x3F80;
    const bf16x8 ones = {one, one, one, one, one, one, one, one};

    const int krow = tid >> 2, kblk = tid & 3;
    const int vrow = tid >> 3, vkc  = tid & 7;

    uint4 kreg = *(const uint4*)(kbase + (size_t)krow * HD + kblk * 8);
    uint4 vreg = *(const uint4*)(vbase + (size_t)vrow * KK + vkc * 8);

    int p = 0;
    for (int kt0 = 0; kt0 < KK; kt0 += 64) {
        *(uint4*)&Ks[p][krow][kblk * 8] = kreg;
        *(uint4*)&Vs[p][vrow][vkc * 8]  = vreg;
        __syncthreads();
        if (kt0 + 64 < KK) {
            kreg = *(const uint4*)(kbase + (size_t)(kt0 + 64 + krow) * HD + kblk * 8);
            vreg = *(const uint4*)(vbase + (size_t)vrow * KK + kt0 + 64 + vkc * 8);
        }

        f32x4 st[4];
        float4 mb[4];
        #pragma unroll
        for (int kt = 0; kt < 4; ++kt) {
            bf16x8 kf = *(const bf16x8*)&Ks[p][kt * 16 + ll][lg * 8];
            mb[kt] = *(const float4*)(mbb + kt0 + kt * 16 + lg * 4);
            st[kt] = __builtin_amdgcn_mfma_f32_16x16x32_bf16(kf, qf, zero, 0, 0, 0);
        }
        #pragma unroll
        for (int kt = 0; kt < 4; ++kt) {
            st[kt][0] = fmaf(qcf, mb[kt].x, st[kt][0]);
            st[kt][1] = fmaf(qcf, mb[kt].y, st[kt][1]);
            st[kt][2] = fmaf(qcf, mb[kt].z, st[kt][2]);
            st[kt][3] = fmaf(qcf, mb[kt].w, st[kt][3]);
        }
        float g0 = fmaxf(fmaxf(st[0][0], st[0][1]), st[0][2]);
        float g1 = fmaxf(fmaxf(st[0][3], st[1][0]), st[1][1]);
        float g2 = fmaxf(fmaxf(st[1][2], st[1][3]), st[2][0]);
        float g3 = fmaxf(fmaxf(st[2][1], st[2][2]), st[2][3]);
        float g4 = fmaxf(fmaxf(st[3][0], st[3][1]), st[3][2]);
        float tmax = fmaxf(fmaxf(fmaxf(g0, g1), fmaxf(g2, g3)), fmaxf(g4, st[3][3]));
        tmax = fmaxf(tmax, __shfl_xor(tmax, 16));
        tmax = fmaxf(tmax, __shfl_xor(tmax, 32));

        if (__any(tmax > m + 8.0f)) {            // deferred rescale
            float mnew = fmaxf(fmaxf(m, tmax), -1e37f);
            float corr = __builtin_amdgcn_exp2f(m - mnew);
            m = mnew;
            #pragma unroll
            for (int r = 0; r < 4; ++r) {
                float cr = __shfl(corr, lg * 4 + r);
                acc0[r] *= cr; acc1[r] *= cr; accl[r] *= cr;
            }
        }
        float msafe = fmaxf(m, -1e37f);

        #pragma unroll
        for (int kt = 0; kt < 4; ++kt) {
            float p0 = __builtin_amdgcn_exp2f(st[kt][0] - msafe);
            float p1 = __builtin_amdgcn_exp2f(st[kt][1] - msafe);
            float p2 = __builtin_amdgcn_exp2f(st[kt][2] - msafe);
            float p3 = __builtin_amdgcn_exp2f(st[kt][3] - msafe);
            uint2 uu;
            uu.x = pkbf(p0, p1);
            uu.y = pkbf(p2, p3);
            *(uint2*)(Pw + ll * 128 + ((kt * 32 + lg * 8) ^ sw)) = uu;
        }

        #pragma unroll
        for (int ks = 0; ks < 2; ++ks) {
            bf16x8 pf = *(const bf16x8*)(Pw + ll * 128 + ((ks * 64 + lg * 16) ^ sw));
            #pragma unroll
            for (int dt = 0; dt < 2; ++dt) {
                bf16x8 vf = *(const bf16x8*)&Vs[p][dt * 16 + ll][ks * 32 + lg * 8];
                if (dt == 0) acc0 = __builtin_amdgcn_mfma_f32_16x16x32_bf16(pf, vf, acc0, 0, 0, 0);
                else         acc1 = __builtin_amdgcn_mfma_f32_16x16x32_bf16(pf, vf, acc1, 0, 0, 0);
            }
            accl = __builtin_amdgcn_mfma_f32_16x16x32_bf16(pf, ones, accl, 0, 0, 0);
        }
        p ^= 1;
    }

    #pragma unroll
    for (int r = 0; r < 4; ++r) {
        float inv = 1.0f / accl[r];
        int q = q0 + lg * 4 + r;
        ushort* orow = ao + ((size_t)b * KK + q) * DD + h * HD;
        orow[ll]      = f2bf(acc0[r] * inv);
        orow[16 + ll] = f2bf(acc1[r] * inv);
    }
}

// ---------------------------------------------------------------------------
extern "C" void kernel_launch(void* const* d_in, const int* in_sizes, int n_in,
                              void* d_out, int out_size, void* d_ws, size_t ws_size,
                              hipStream_t stream)
{
    const float* x        = (const float*)d_in[0];
    const int*   coords   = (const int*)  d_in[1];
    const int*   is_ctx   = (const int*)  d_in[2];
    const int*   img_sz   = (const int*)  d_in[3];
    const float* Wq       = (const float*)d_in[4];
    const float* bq       = (const float*)d_in[5];
    const float* Wk       = (const float*)d_in[6];
    const float* bk       = (const float*)d_in[7];
    const float* Wv       = (const float*)d_in[8];
    const float* bv       = (const float*)d_in[9];
    const float* Wo       = (const float*)d_in[10];
    const float* bo       = (const float*)d_in[11];
    const float* rope     = (const float*)d_in[12];

    int max_pos = in_sizes[12] / (QUARTER * 2);   // 224

    const size_t NTOK = (size_t)BB * KK;          // 8192
    const size_t NELT = NTOK * DD;                // 2,097,152 elements

    char* ws = (char*)d_ws;
    ushort* xr16  = (ushort*)(ws);                     // 4 MB
    ushort* qbf   = (ushort*)(ws + NELT * 2);          // 4 MB
    ushort* kbf   = (ushort*)(ws + NELT * 4);          // 4 MB
    ushort* vtbf  = (ushort*)(ws + NELT * 6);          // 4 MB
    ushort* ao16  = (ushort*)(ws + NELT * 8);          // 4 MB
    ushort* wt    = (ushort*)(ws + NELT * 10);         // 512 KB
    float*  mbias = (float*) (ws + NELT * 10 + 524288);          // 32 KB
    float* outp = (float*)d_out;

    // 1) RoPE -> bf16 xr + mask bias array
    {
        int total = BB * KK * HALF;
        rope_kernel<<<(total + 255) / 256, 256, 0, stream>>>(
            x, coords, rope, img_sz, is_ctx, max_pos, xr16, mbias);
    }
    // 2) weight prep: transpose + bf16 (+ SCALE2F fold into Wq)
    wprep_kernel<<<dim3(4, 4, 4), 256, 0, stream>>>(Wq, Wk, Wv, Wo, wt);
    // 3) QKV projections (bf16 MFMA, 64x64 pipelined tiles)
    mfma_gemm_kernel<<<dim3(NTOK / 64, DD / 64, 3), 256, 0, stream>>>(
        xr16, wt, bq, bk, bv, qbf, kbf, vtbf, 1);
    // 4) attention (LDS-staged double-buffered K/V) -> bf16 ao
    attn_mfma_kernel<<<dim3(KK / 64, HH, BB), 256, 0, stream>>>(
        qbf, kbf, vtbf, is_ctx, mbias, ao16);
    // 5) output projection (bf16 MFMA, fp32 out)
    mfma_gemm_kernel<<<dim3(NTOK / 64, DD / 64, 1), 256, 0, stream>>>(
        ao16, wt, bo, bo, bo, outp, outp, outp, 0);
}